// Round 1
// baseline (442.461 us; speedup 1.0000x reference)
//
#include <hip/hip_runtime.h>
#include <hip/hip_bf16.h>

// Problem constants (from reference)
#define T_DIM   16
#define N_NODES 10000
#define FIN     32
#define FH      64
#define NE      160000

// ---------------------------------------------------------------------------
// Kernel 1: degree (float, weighted, over dst) + in-edge count histogram
// ---------------------------------------------------------------------------
__global__ void build_deg_kernel(const int* __restrict__ ei,
                                 const float* __restrict__ w,
                                 float* __restrict__ deg,
                                 int* __restrict__ cnt) {
    int e = blockIdx.x * blockDim.x + threadIdx.x;
    if (e < NE) {
        int d = ei[NE + e];          // dst row of edge_index (2, E)
        atomicAdd(&deg[d], w[e]);
        atomicAdd(&cnt[d], 1);
    }
}

// ---------------------------------------------------------------------------
// Kernel 2: add self-loop weight 1, dis = rsqrt(deg), selfnorm = dis^2
// (deg >= 1 always because of the self loop, so no deg>0 branch needed)
// ---------------------------------------------------------------------------
__global__ void finish_deg_kernel(const float* __restrict__ deg,
                                  float* __restrict__ dis,
                                  float* __restrict__ selfn) {
    int n = blockIdx.x * blockDim.x + threadIdx.x;
    if (n < N_NODES) {
        float d = deg[n] + 1.0f;
        float r = rsqrtf(d);
        dis[n] = r;
        selfn[n] = r * r;
    }
}

// ---------------------------------------------------------------------------
// Kernel 3: single-block exclusive scan of cnt -> rowptr (N=10000)
// ---------------------------------------------------------------------------
__global__ void scan_kernel(const int* __restrict__ cnt,
                            int* __restrict__ rowptr, int n) {
    __shared__ int sm[1024];
    __shared__ int s_carry;
    int tid = threadIdx.x;
    if (tid == 0) { s_carry = 0; rowptr[0] = 0; }
    __syncthreads();
    for (int base = 0; base < n; base += 1024) {
        int i = base + tid;
        int v = (i < n) ? cnt[i] : 0;
        sm[tid] = v;
        __syncthreads();
        for (int off = 1; off < 1024; off <<= 1) {
            int t = (tid >= off) ? sm[tid - off] : 0;
            __syncthreads();
            sm[tid] += t;
            __syncthreads();
        }
        int carry = s_carry;
        if (i < n) rowptr[i + 1] = carry + sm[tid];
        __syncthreads();
        if (tid == 0) s_carry = carry + sm[1023];
        __syncthreads();
    }
}

// ---------------------------------------------------------------------------
// Kernel 4: scatter edges into dst-sorted CSR with precomputed norm
// ---------------------------------------------------------------------------
__global__ void build_csr_kernel(const int* __restrict__ ei,
                                 const float* __restrict__ w,
                                 const float* __restrict__ dis,
                                 const int* __restrict__ rowptr,
                                 int* __restrict__ cursor,
                                 int* __restrict__ col,
                                 float* __restrict__ val) {
    int e = blockIdx.x * blockDim.x + threadIdx.x;
    if (e < NE) {
        int s = ei[e];
        int d = ei[NE + e];
        int pos = rowptr[d] + atomicAdd(&cursor[d], 1);
        col[pos] = s;
        val[pos] = dis[s] * w[e] * dis[d];
    }
}

// ---------------------------------------------------------------------------
// Kernel 5 (fused layer 1 + dense 32->64->32):
//   agg = A.x  (gather over CSR, 32 feats)
//   h   = relu(agg @ W1 + b1)      (64)
//   g   = h @ W2                   (32)   [b2 added after layer-2 aggregation]
// One 32-lane group per (t, n); 8 groups per 256-thread block.
// ---------------------------------------------------------------------------
__global__ __launch_bounds__(256) void layer1_kernel(
    const float* __restrict__ x,
    const int* __restrict__ rowptr,
    const int* __restrict__ col,
    const float* __restrict__ val,
    const float* __restrict__ selfn,
    const float* __restrict__ W1,
    const float* __restrict__ b1,
    const float* __restrict__ W2,
    float* __restrict__ g) {
    __shared__ float sW1[FIN * FH];
    __shared__ float sW2[FH * FIN];
    __shared__ float sB1[FH];
    __shared__ float sAcc[8][FIN];
    __shared__ float sH[8][FH];

    int tid = threadIdx.x;
    for (int i = tid; i < FIN * FH; i += 256) sW1[i] = W1[i];
    for (int i = tid; i < FH * FIN; i += 256) sW2[i] = W2[i];
    if (tid < FH) sB1[tid] = b1[tid];

    int grp = tid >> 5;
    int lane = tid & 31;
    int gid = blockIdx.x * 8 + grp;      // 0 .. T*N-1
    int t = gid / N_NODES;
    int n = gid - t * N_NODES;

    const float* xt = x + (size_t)t * N_NODES * FIN;

    // aggregation (gather), feature = lane
    float acc = selfn[n] * xt[n * FIN + lane];
    int e0 = rowptr[n], e1 = rowptr[n + 1];
    for (int e = e0; e < e1; ++e) {
        int c = col[e];
        float v = val[e];
        acc = fmaf(v, xt[c * FIN + lane], acc);
    }
    sAcc[grp][lane] = acc;
    __syncthreads();

    // h_j = b1_j + sum_f acc_f * W1[f][j]; lane does j = lane, lane+32
    float h0 = sB1[lane];
    float h1 = sB1[lane + 32];
#pragma unroll
    for (int f = 0; f < FIN; ++f) {
        float a = sAcc[grp][f];
        h0 = fmaf(a, sW1[f * FH + lane], h0);
        h1 = fmaf(a, sW1[f * FH + lane + 32], h1);
    }
    h0 = fmaxf(h0, 0.0f);
    h1 = fmaxf(h1, 0.0f);
    sH[grp][lane] = h0;
    sH[grp][lane + 32] = h1;
    __syncthreads();

    // g_k = sum_j h_j * W2[j][k]
    float gk = 0.0f;
#pragma unroll
    for (int j = 0; j < FH; ++j) gk = fmaf(sH[grp][j], sW2[j * FIN + lane], gk);

    g[(size_t)gid * FIN + lane] = gk;
}

// ---------------------------------------------------------------------------
// Kernel 6 (layer 2 aggregation): out = A.g + b2; also zero the tail scalar
// ---------------------------------------------------------------------------
__global__ __launch_bounds__(256) void layer2_kernel(
    const float* __restrict__ g,
    const int* __restrict__ rowptr,
    const int* __restrict__ col,
    const float* __restrict__ val,
    const float* __restrict__ selfn,
    const float* __restrict__ b2,
    float* __restrict__ out, int out_size) {
    int tid = threadIdx.x;
    int grp = tid >> 5;
    int lane = tid & 31;
    int gid = blockIdx.x * 8 + grp;
    int t = gid / N_NODES;
    int n = gid - t * N_NODES;

    const float* gt = g + (size_t)t * N_NODES * FIN;

    float acc = b2[lane] + selfn[n] * gt[n * FIN + lane];
    int e0 = rowptr[n], e1 = rowptr[n + 1];
    for (int e = e0; e < e1; ++e) {
        acc = fmaf(val[e], gt[col[e] * FIN + lane], acc);
    }
    out[(size_t)gid * FIN + lane] = acc;

    // second tuple element (scalar 0) and any tail
    if (blockIdx.x == 0 && tid == 0) {
        for (int i = T_DIM * N_NODES * FIN; i < out_size; ++i) out[i] = 0.0f;
    }
}

// ---------------------------------------------------------------------------
extern "C" void kernel_launch(void* const* d_in, const int* in_sizes, int n_in,
                              void* d_out, int out_size, void* d_ws, size_t ws_size,
                              hipStream_t stream) {
    const float* x  = (const float*)d_in[0];
    const int*   ei = (const int*)d_in[1];     // (2, E) int32: [src | dst]
    const float* w  = (const float*)d_in[2];
    // d_in[3] missing_mask: unused by reference math
    const float* W1 = (const float*)d_in[4];
    const float* b1 = (const float*)d_in[5];
    const float* W2 = (const float*)d_in[6];
    const float* b2 = (const float*)d_in[7];
    float* out = (float*)d_out;

    char* p = (char*)d_ws;
    float* g      = (float*)p; p += sizeof(float) * (size_t)T_DIM * N_NODES * FIN;
    float* deg    = (float*)p; p += sizeof(float) * N_NODES;
    float* dis    = (float*)p; p += sizeof(float) * N_NODES;
    float* selfn  = (float*)p; p += sizeof(float) * N_NODES;
    int*   cnt    = (int*)p;   p += sizeof(int) * N_NODES;
    int*   rowptr = (int*)p;   p += sizeof(int) * (N_NODES + 1);
    int*   cursor = (int*)p;   p += sizeof(int) * N_NODES;
    int*   colA   = (int*)p;   p += sizeof(int) * NE;
    float* valA   = (float*)p; p += sizeof(float) * NE;

    hipMemsetAsync(deg, 0, sizeof(float) * N_NODES, stream);
    hipMemsetAsync(cnt, 0, sizeof(int) * N_NODES, stream);
    hipMemsetAsync(cursor, 0, sizeof(int) * N_NODES, stream);

    build_deg_kernel<<<(NE + 255) / 256, 256, 0, stream>>>(ei, w, deg, cnt);
    finish_deg_kernel<<<(N_NODES + 255) / 256, 256, 0, stream>>>(deg, dis, selfn);
    scan_kernel<<<1, 1024, 0, stream>>>(cnt, rowptr, N_NODES);
    build_csr_kernel<<<(NE + 255) / 256, 256, 0, stream>>>(ei, w, dis, rowptr,
                                                           cursor, colA, valA);
    layer1_kernel<<<(T_DIM * N_NODES) / 8, 256, 0, stream>>>(
        x, rowptr, colA, valA, selfn, W1, b1, W2, g);
    layer2_kernel<<<(T_DIM * N_NODES) / 8, 256, 0, stream>>>(
        g, rowptr, colA, valA, selfn, b2, out, out_size);
}

// Round 2
// 363.210 us; speedup vs baseline: 1.2182x; 1.2182x over previous
//
#include <hip/hip_runtime.h>
#include <hip/hip_bf16.h>

// Problem constants (from reference)
#define T_DIM   16
#define N_NODES 10000
#define FIN     32
#define FH      64
#define NE      160000
#define GPB     8        // 32-lane groups per 256-thread block

// ---------------------------------------------------------------------------
// Kernel 1: degree (float, weighted, over dst) + in-edge count histogram
// ---------------------------------------------------------------------------
__global__ void build_deg_kernel(const int* __restrict__ ei,
                                 const float* __restrict__ w,
                                 float* __restrict__ deg,
                                 int* __restrict__ cnt) {
    int e = blockIdx.x * blockDim.x + threadIdx.x;
    if (e < NE) {
        int d = ei[NE + e];          // dst row of edge_index (2, E)
        atomicAdd(&deg[d], w[e]);
        atomicAdd(&cnt[d], 1);
    }
}

// ---------------------------------------------------------------------------
// Kernel 2: add self-loop weight 1, dis = rsqrt(deg), selfnorm = dis^2
// ---------------------------------------------------------------------------
__global__ void finish_deg_kernel(const float* __restrict__ deg,
                                  float* __restrict__ dis,
                                  float* __restrict__ selfn) {
    int n = blockIdx.x * blockDim.x + threadIdx.x;
    if (n < N_NODES) {
        float d = deg[n] + 1.0f;
        float r = rsqrtf(d);
        dis[n] = r;
        selfn[n] = r * r;
    }
}

// ---------------------------------------------------------------------------
// Kernel 3: single-pass exclusive scan of cnt -> rowptr (N=10000)
// 1024 threads x 10 elements each; one block-scan of partials.
// ---------------------------------------------------------------------------
__global__ __launch_bounds__(1024) void scan_kernel(const int* __restrict__ cnt,
                                                    int* __restrict__ rowptr) {
    __shared__ int sm[1024];
    int tid = threadIdx.x;
    int base = tid * 10;
    int v[10];
    int s = 0;
#pragma unroll
    for (int k = 0; k < 10; ++k) {
        int i = base + k;
        v[k] = (i < N_NODES) ? cnt[i] : 0;
        s += v[k];
    }
    sm[tid] = s;
    __syncthreads();
    for (int off = 1; off < 1024; off <<= 1) {
        int t = (tid >= off) ? sm[tid - off] : 0;
        __syncthreads();
        sm[tid] += t;
        __syncthreads();
    }
    int run = (tid > 0) ? sm[tid - 1] : 0;   // exclusive prefix of this thread
#pragma unroll
    for (int k = 0; k < 10; ++k) {
        int i = base + k;
        if (i <= N_NODES) rowptr[i] = run;
        run += v[k];
    }
}

// ---------------------------------------------------------------------------
// Kernel 4: scatter edges into dst-sorted CSR with precomputed norm
// ---------------------------------------------------------------------------
__global__ void build_csr_kernel(const int* __restrict__ ei,
                                 const float* __restrict__ w,
                                 const float* __restrict__ dis,
                                 const int* __restrict__ rowptr,
                                 int* __restrict__ cursor,
                                 int* __restrict__ col,
                                 float* __restrict__ val) {
    int e = blockIdx.x * blockDim.x + threadIdx.x;
    if (e < NE) {
        int s = ei[e];
        int d = ei[NE + e];
        int pos = rowptr[d] + atomicAdd(&cursor[d], 1);
        col[pos] = s;
        val[pos] = dis[s] * w[e] * dis[d];
    }
}

// ---------------------------------------------------------------------------
// Kernel 5 (fused layer 1): one 32-lane group per NODE, all 16 t in registers.
//   acc[t] = (A.x)[t,n,:]   (gather; col/val read once, 16-way ILP per edge)
//   h      = relu(acc @ W1 + b1)   (64, t-chunked by 8)
//   g      = h @ W2                 (32)  -> stored (N, T, F) layout
// LDS is wave-private (group = half-wave): no __syncthreads needed.
// ---------------------------------------------------------------------------
__global__ __launch_bounds__(256) void layer1_kernel(
    const float* __restrict__ x,
    const int* __restrict__ rowptr,
    const int* __restrict__ col,
    const float* __restrict__ val,
    const float* __restrict__ selfn,
    const float* __restrict__ W1,
    const float* __restrict__ b1,
    const float* __restrict__ W2,
    float* __restrict__ g) {
    __shared__ float sAcc[GPB][T_DIM][FIN];   // 16 KB
    __shared__ float sH[GPB][8][FH];          // 16 KB

    int tid = threadIdx.x;
    int grp = tid >> 5;
    int lane = tid & 31;
    int n = blockIdx.x * GPB + grp;           // grid = N/GPB exactly

    // ---- gather phase: acc[t] over CSR row n ----
    float sn = selfn[n];
    float acc[T_DIM];
    const float* xb = x + n * FIN + lane;
#pragma unroll
    for (int t = 0; t < T_DIM; ++t)
        acc[t] = sn * xb[(size_t)t * N_NODES * FIN];

    int e0 = rowptr[n], e1 = rowptr[n + 1];
    for (int e = e0; e < e1; ++e) {
        int c = col[e];
        float v = val[e];
        const float* xc = x + c * FIN + lane;
#pragma unroll
        for (int t = 0; t < T_DIM; ++t)
            acc[t] = fmaf(v, xc[(size_t)t * N_NODES * FIN], acc[t]);
    }
#pragma unroll
    for (int t = 0; t < T_DIM; ++t) sAcc[grp][t][lane] = acc[t];

    // ---- dense phase: weights from global (L1-resident), t-chunks of 8 ----
    float bias0 = b1[lane];
    float bias1 = b1[lane + 32];
    for (int ch = 0; ch < 2; ++ch) {
        float h0[8], h1[8];
#pragma unroll
        for (int tt = 0; tt < 8; ++tt) { h0[tt] = bias0; h1[tt] = bias1; }
#pragma unroll
        for (int f = 0; f < FIN; ++f) {
            float w0 = W1[f * FH + lane];
            float w1 = W1[f * FH + lane + 32];
#pragma unroll
            for (int tt = 0; tt < 8; ++tt) {
                float a = sAcc[grp][ch * 8 + tt][f];   // broadcast read
                h0[tt] = fmaf(a, w0, h0[tt]);
                h1[tt] = fmaf(a, w1, h1[tt]);
            }
        }
#pragma unroll
        for (int tt = 0; tt < 8; ++tt) {
            sH[grp][tt][lane] = fmaxf(h0[tt], 0.0f);
            sH[grp][tt][lane + 32] = fmaxf(h1[tt], 0.0f);
        }
        float gk[8];
#pragma unroll
        for (int tt = 0; tt < 8; ++tt) gk[tt] = 0.0f;
#pragma unroll
        for (int j = 0; j < FH; ++j) {
            float w = W2[j * FIN + lane];
#pragma unroll
            for (int tt = 0; tt < 8; ++tt)
                gk[tt] = fmaf(sH[grp][tt][j], w, gk[tt]);   // broadcast read
        }
#pragma unroll
        for (int tt = 0; tt < 8; ++tt)
            g[(size_t)n * (T_DIM * FIN) + (ch * 8 + tt) * FIN + lane] = gk[tt];
    }
}

// ---------------------------------------------------------------------------
// Kernel 6 (layer 2 aggregation): one group per node, all 16 t.
// g is (N, T, F): per edge the 16 gathers are one contiguous 2 KB region
// (immediate offsets). out written back in (T, N, F) order + b2.
// ---------------------------------------------------------------------------
__global__ __launch_bounds__(256) void layer2_kernel(
    const float* __restrict__ g,
    const int* __restrict__ rowptr,
    const int* __restrict__ col,
    const float* __restrict__ val,
    const float* __restrict__ selfn,
    const float* __restrict__ b2,
    float* __restrict__ out, int out_size) {
    int tid = threadIdx.x;
    int grp = tid >> 5;
    int lane = tid & 31;
    int n = blockIdx.x * GPB + grp;

    float sn = selfn[n];
    float b = b2[lane];
    float acc[T_DIM];
    const float* gn = g + (size_t)n * (T_DIM * FIN) + lane;
#pragma unroll
    for (int t = 0; t < T_DIM; ++t) acc[t] = b + sn * gn[t * FIN];

    int e0 = rowptr[n], e1 = rowptr[n + 1];
    for (int e = e0; e < e1; ++e) {
        int c = col[e];
        float v = val[e];
        const float* gc = g + (size_t)c * (T_DIM * FIN) + lane;
#pragma unroll
        for (int t = 0; t < T_DIM; ++t)
            acc[t] = fmaf(v, gc[t * FIN], acc[t]);
    }
#pragma unroll
    for (int t = 0; t < T_DIM; ++t)
        out[(size_t)t * N_NODES * FIN + n * FIN + lane] = acc[t];

    // second tuple element (scalar 0) and any tail
    if (blockIdx.x == 0 && tid == 0) {
        for (int i = T_DIM * N_NODES * FIN; i < out_size; ++i) out[i] = 0.0f;
    }
}

// ---------------------------------------------------------------------------
extern "C" void kernel_launch(void* const* d_in, const int* in_sizes, int n_in,
                              void* d_out, int out_size, void* d_ws, size_t ws_size,
                              hipStream_t stream) {
    const float* x  = (const float*)d_in[0];
    const int*   ei = (const int*)d_in[1];     // (2, E) int32: [src | dst]
    const float* w  = (const float*)d_in[2];
    // d_in[3] missing_mask: unused by reference math
    const float* W1 = (const float*)d_in[4];
    const float* b1 = (const float*)d_in[5];
    const float* W2 = (const float*)d_in[6];
    const float* b2 = (const float*)d_in[7];
    float* out = (float*)d_out;

    char* p = (char*)d_ws;
    float* g      = (float*)p; p += sizeof(float) * (size_t)T_DIM * N_NODES * FIN;
    // deg, cnt, cursor contiguous -> single memset
    float* deg    = (float*)p; p += sizeof(float) * N_NODES;
    int*   cnt    = (int*)p;   p += sizeof(int) * N_NODES;
    int*   cursor = (int*)p;   p += sizeof(int) * N_NODES;
    float* dis    = (float*)p; p += sizeof(float) * N_NODES;
    float* selfn  = (float*)p; p += sizeof(float) * N_NODES;
    int*   rowptr = (int*)p;   p += sizeof(int) * (N_NODES + 1);
    int*   colA   = (int*)p;   p += sizeof(int) * NE;
    float* valA   = (float*)p; p += sizeof(float) * NE;

    hipMemsetAsync(deg, 0, sizeof(float) * N_NODES * 3, stream);

    build_deg_kernel<<<(NE + 255) / 256, 256, 0, stream>>>(ei, w, deg, cnt);
    finish_deg_kernel<<<(N_NODES + 255) / 256, 256, 0, stream>>>(deg, dis, selfn);
    scan_kernel<<<1, 1024, 0, stream>>>(cnt, rowptr);
    build_csr_kernel<<<(NE + 255) / 256, 256, 0, stream>>>(ei, w, dis, rowptr,
                                                           cursor, colA, valA);
    layer1_kernel<<<N_NODES / GPB, 256, 0, stream>>>(
        x, rowptr, colA, valA, selfn, W1, b1, W2, g);
    layer2_kernel<<<N_NODES / GPB, 256, 0, stream>>>(
        g, rowptr, colA, valA, selfn, b2, out, out_size);
}

// Round 3
// 244.039 us; speedup vs baseline: 1.8131x; 1.4883x over previous
//
#include <hip/hip_runtime.h>
#include <hip/hip_bf16.h>

// Problem constants (from reference)
#define T_DIM   16
#define N_NODES 10000
#define FIN     32
#define FH      64
#define NE      160000
#define GPB     8        // 32-lane groups per 256-thread block
#define TB      2        // timesteps per chunk
#define NCHUNK  (T_DIM / TB)   // 8 chunks -> one per XCD via bid%8
#define NF      (N_NODES * FIN)

// ---------------------------------------------------------------------------
// Kernel 1: degree (float, weighted, over dst) + in-edge count histogram
// ---------------------------------------------------------------------------
__global__ void build_deg_kernel(const int* __restrict__ ei,
                                 const float* __restrict__ w,
                                 float* __restrict__ deg,
                                 int* __restrict__ cnt) {
    int e = blockIdx.x * blockDim.x + threadIdx.x;
    if (e < NE) {
        int d = ei[NE + e];          // dst row of edge_index (2, E)
        atomicAdd(&deg[d], w[e]);
        atomicAdd(&cnt[d], 1);
    }
}

// ---------------------------------------------------------------------------
// Kernel 2: add self-loop weight 1, dis = rsqrt(deg), selfnorm = dis^2
// ---------------------------------------------------------------------------
__global__ void finish_deg_kernel(const float* __restrict__ deg,
                                  float* __restrict__ dis,
                                  float* __restrict__ selfn) {
    int n = blockIdx.x * blockDim.x + threadIdx.x;
    if (n < N_NODES) {
        float d = deg[n] + 1.0f;
        float r = rsqrtf(d);
        dis[n] = r;
        selfn[n] = r * r;
    }
}

// ---------------------------------------------------------------------------
// Kernel 3: single-pass exclusive scan of cnt -> rowptr (N=10000)
// ---------------------------------------------------------------------------
__global__ __launch_bounds__(1024) void scan_kernel(const int* __restrict__ cnt,
                                                    int* __restrict__ rowptr) {
    __shared__ int sm[1024];
    int tid = threadIdx.x;
    int base = tid * 10;
    int v[10];
    int s = 0;
#pragma unroll
    for (int k = 0; k < 10; ++k) {
        int i = base + k;
        v[k] = (i < N_NODES) ? cnt[i] : 0;
        s += v[k];
    }
    sm[tid] = s;
    __syncthreads();
    for (int off = 1; off < 1024; off <<= 1) {
        int t = (tid >= off) ? sm[tid - off] : 0;
        __syncthreads();
        sm[tid] += t;
        __syncthreads();
    }
    int run = (tid > 0) ? sm[tid - 1] : 0;
#pragma unroll
    for (int k = 0; k < 10; ++k) {
        int i = base + k;
        if (i <= N_NODES) rowptr[i] = run;
        run += v[k];
    }
}

// ---------------------------------------------------------------------------
// Kernel 4: scatter edges into dst-sorted CSR, packed {col, norm-bits}
// ---------------------------------------------------------------------------
__global__ void build_csr_kernel(const int* __restrict__ ei,
                                 const float* __restrict__ w,
                                 const float* __restrict__ dis,
                                 const int* __restrict__ rowptr,
                                 int* __restrict__ cursor,
                                 int2* __restrict__ edges) {
    int e = blockIdx.x * blockDim.x + threadIdx.x;
    if (e < NE) {
        int s = ei[e];
        int d = ei[NE + e];
        int pos = rowptr[d] + atomicAdd(&cursor[d], 1);
        edges[pos] = make_int2(s, __float_as_int(dis[s] * w[e] * dis[d]));
    }
}

// ---------------------------------------------------------------------------
// Kernel 5 (fused layer 1): block = (t-chunk tc, node-block nb),
// blockIdx = nb*8 + tc so XCD(bid)=bid%8 pins chunk->XCD: per-XCD x working
// set = x[2tc:2tc+2] = 2.56 MB < 4 MB L2 (compulsory fills only).
// One 32-lane group per node; TB=2 timesteps in registers.
//   acc[tt] = (A.x)[t0+tt, n, :]   (CSR gather, edges packed int2)
//   h = relu(acc @ W1 + b1); g = h @ W2  -> g stored (N, T, F)
// ---------------------------------------------------------------------------
__global__ __launch_bounds__(256) void layer1_kernel(
    const float* __restrict__ x,
    const int* __restrict__ rowptr,
    const int2* __restrict__ edges,
    const float* __restrict__ selfn,
    const float* __restrict__ W1,
    const float* __restrict__ b1,
    const float* __restrict__ W2,
    float* __restrict__ g) {
    __shared__ float sW1[FIN * FH];     // 8 KB
    __shared__ float sW2[FH * FIN];     // 8 KB
    __shared__ float sB1[FH];
    __shared__ float sAcc[GPB][TB][FIN];  // 2 KB
    __shared__ float sH[GPB][TB][FH];     // 4 KB

    int tid = threadIdx.x;
    // stage weights (visibility guaranteed by the barrier after the gather)
    for (int i = tid; i < FIN * FH; i += 256) sW1[i] = W1[i];
    for (int i = tid; i < FH * FIN; i += 256) sW2[i] = W2[i];
    if (tid < FH) sB1[tid] = b1[tid];

    int b = blockIdx.x;
    int tc = b & (NCHUNK - 1);
    int nb = b >> 3;
    int grp = tid >> 5;
    int lane = tid & 31;
    int n = nb * GPB + grp;

    const float* x0 = x + (size_t)(tc * TB) * NF;   // slice t0; t0+1 at +NF

    float sn = selfn[n];
    float a0 = sn * x0[n * FIN + lane];
    float a1 = sn * x0[NF + n * FIN + lane];

    int e = rowptr[n], e1 = rowptr[n + 1];
    for (; e + 4 <= e1; e += 4) {
        int2 p0 = edges[e], p1 = edges[e + 1], p2 = edges[e + 2], p3 = edges[e + 3];
        int c0 = p0.x * FIN + lane, c1 = p1.x * FIN + lane;
        int c2 = p2.x * FIN + lane, c3 = p3.x * FIN + lane;
        float x00 = x0[c0], x01 = x0[NF + c0];
        float x10 = x0[c1], x11 = x0[NF + c1];
        float x20 = x0[c2], x21 = x0[NF + c2];
        float x30 = x0[c3], x31 = x0[NF + c3];
        float v0 = __int_as_float(p0.y), v1 = __int_as_float(p1.y);
        float v2 = __int_as_float(p2.y), v3 = __int_as_float(p3.y);
        a0 = fmaf(v0, x00, a0); a1 = fmaf(v0, x01, a1);
        a0 = fmaf(v1, x10, a0); a1 = fmaf(v1, x11, a1);
        a0 = fmaf(v2, x20, a0); a1 = fmaf(v2, x21, a1);
        a0 = fmaf(v3, x30, a0); a1 = fmaf(v3, x31, a1);
    }
    for (; e < e1; ++e) {
        int2 p = edges[e];
        float v = __int_as_float(p.y);
        int c = p.x * FIN + lane;
        a0 = fmaf(v, x0[c], a0);
        a1 = fmaf(v, x0[NF + c], a1);
    }
    sAcc[grp][0][lane] = a0;
    sAcc[grp][1][lane] = a1;
    __syncthreads();   // weights staged + (own-group) acc visible

    // dense: h = relu(acc @ W1 + b1), lane covers j = lane, lane+32
    float h0 = sB1[lane], h1 = sB1[lane + 32];
    float h2 = h0, h3 = h1;
#pragma unroll
    for (int f = 0; f < FIN; ++f) {
        float w0 = sW1[f * FH + lane];
        float w1 = sW1[f * FH + lane + 32];
        float af0 = sAcc[grp][0][f];   // broadcast
        float af1 = sAcc[grp][1][f];
        h0 = fmaf(af0, w0, h0); h1 = fmaf(af0, w1, h1);
        h2 = fmaf(af1, w0, h2); h3 = fmaf(af1, w1, h3);
    }
    sH[grp][0][lane] = fmaxf(h0, 0.0f);
    sH[grp][0][lane + 32] = fmaxf(h1, 0.0f);
    sH[grp][1][lane] = fmaxf(h2, 0.0f);
    sH[grp][1][lane + 32] = fmaxf(h3, 0.0f);

    float g0 = 0.0f, g1 = 0.0f;
#pragma unroll
    for (int j = 0; j < FH; ++j) {
        float w = sW2[j * FIN + lane];
        g0 = fmaf(sH[grp][0][j], w, g0);   // broadcast
        g1 = fmaf(sH[grp][1][j], w, g1);
    }
    size_t gb = (size_t)n * (T_DIM * FIN) + (tc * TB) * FIN + lane;
    g[gb] = g0;
    g[gb + FIN] = g1;
}

// ---------------------------------------------------------------------------
// Kernel 6 (layer 2 aggregation): same (tc, nb) decomposition; per-XCD g
// working set = g[:, 2tc:2tc+2, :] = 2.56 MB (same XCD that wrote it).
// Per edge the TB=2 gathers are one contiguous 256 B region of g (N,T,F).
// ---------------------------------------------------------------------------
__global__ __launch_bounds__(256) void layer2_kernel(
    const float* __restrict__ g,
    const int* __restrict__ rowptr,
    const int2* __restrict__ edges,
    const float* __restrict__ selfn,
    const float* __restrict__ b2,
    float* __restrict__ out, int out_size) {
    int b = blockIdx.x;
    int tc = b & (NCHUNK - 1);
    int nb = b >> 3;
    int tid = threadIdx.x;
    int grp = tid >> 5;
    int lane = tid & 31;
    int n = nb * GPB + grp;
    int t0 = tc * TB;

    float sn = selfn[n];
    float bb = b2[lane];
    const float* gn = g + (size_t)n * (T_DIM * FIN) + t0 * FIN + lane;
    float a0 = bb + sn * gn[0];
    float a1 = bb + sn * gn[FIN];

    int e = rowptr[n], e1 = rowptr[n + 1];
    for (; e + 4 <= e1; e += 4) {
        int2 p0 = edges[e], p1 = edges[e + 1], p2 = edges[e + 2], p3 = edges[e + 3];
        const float* g0p = g + (size_t)p0.x * (T_DIM * FIN) + t0 * FIN + lane;
        const float* g1p = g + (size_t)p1.x * (T_DIM * FIN) + t0 * FIN + lane;
        const float* g2p = g + (size_t)p2.x * (T_DIM * FIN) + t0 * FIN + lane;
        const float* g3p = g + (size_t)p3.x * (T_DIM * FIN) + t0 * FIN + lane;
        float x00 = g0p[0], x01 = g0p[FIN];
        float x10 = g1p[0], x11 = g1p[FIN];
        float x20 = g2p[0], x21 = g2p[FIN];
        float x30 = g3p[0], x31 = g3p[FIN];
        float v0 = __int_as_float(p0.y), v1 = __int_as_float(p1.y);
        float v2 = __int_as_float(p2.y), v3 = __int_as_float(p3.y);
        a0 = fmaf(v0, x00, a0); a1 = fmaf(v0, x01, a1);
        a0 = fmaf(v1, x10, a0); a1 = fmaf(v1, x11, a1);
        a0 = fmaf(v2, x20, a0); a1 = fmaf(v2, x21, a1);
        a0 = fmaf(v3, x30, a0); a1 = fmaf(v3, x31, a1);
    }
    for (; e < e1; ++e) {
        int2 p = edges[e];
        float v = __int_as_float(p.y);
        const float* gp = g + (size_t)p.x * (T_DIM * FIN) + t0 * FIN + lane;
        a0 = fmaf(v, gp[0], a0);
        a1 = fmaf(v, gp[FIN], a1);
    }

    out[(size_t)t0 * NF + n * FIN + lane] = a0;
    out[(size_t)(t0 + 1) * NF + n * FIN + lane] = a1;

    // second tuple element (scalar 0) and any tail
    if (b == 0 && tid == 0) {
        for (int i = T_DIM * NF; i < out_size; ++i) out[i] = 0.0f;
    }
}

// ---------------------------------------------------------------------------
extern "C" void kernel_launch(void* const* d_in, const int* in_sizes, int n_in,
                              void* d_out, int out_size, void* d_ws, size_t ws_size,
                              hipStream_t stream) {
    const float* x  = (const float*)d_in[0];
    const int*   ei = (const int*)d_in[1];     // (2, E) int32: [src | dst]
    const float* w  = (const float*)d_in[2];
    // d_in[3] missing_mask: unused by reference math
    const float* W1 = (const float*)d_in[4];
    const float* b1 = (const float*)d_in[5];
    const float* W2 = (const float*)d_in[6];
    const float* b2 = (const float*)d_in[7];
    float* out = (float*)d_out;

    char* p = (char*)d_ws;
    float* g      = (float*)p; p += sizeof(float) * (size_t)T_DIM * NF;
    // deg, cnt, cursor contiguous -> single memset
    float* deg    = (float*)p; p += sizeof(float) * N_NODES;
    int*   cnt    = (int*)p;   p += sizeof(int) * N_NODES;
    int*   cursor = (int*)p;   p += sizeof(int) * N_NODES;
    float* dis    = (float*)p; p += sizeof(float) * N_NODES;
    float* selfn  = (float*)p; p += sizeof(float) * N_NODES;
    int*   rowptr = (int*)p;   p += sizeof(int) * (N_NODES + 1);
    int2*  edges  = (int2*)p;  p += sizeof(int2) * NE;

    hipMemsetAsync(deg, 0, sizeof(float) * N_NODES * 3, stream);

    build_deg_kernel<<<(NE + 255) / 256, 256, 0, stream>>>(ei, w, deg, cnt);
    finish_deg_kernel<<<(N_NODES + 255) / 256, 256, 0, stream>>>(deg, dis, selfn);
    scan_kernel<<<1, 1024, 0, stream>>>(cnt, rowptr);
    build_csr_kernel<<<(NE + 255) / 256, 256, 0, stream>>>(ei, w, dis, rowptr,
                                                           cursor, edges);
    layer1_kernel<<<(N_NODES / GPB) * NCHUNK, 256, 0, stream>>>(
        x, rowptr, edges, selfn, W1, b1, W2, g);
    layer2_kernel<<<(N_NODES / GPB) * NCHUNK, 256, 0, stream>>>(
        g, rowptr, edges, selfn, b2, out, out_size);
}